// Round 1
// 492.970 us; speedup vs baseline: 1.0948x; 1.0948x over previous
//
#include <hip/hip_runtime.h>

#define B 8
#define N 512
#define D 256
#define DH 64
#define NEG_INF (-1.0e9f)
#define ROWS 8            // x-rows per qkv block

// ---- fused kernel geometry ----
#define TI 8                          // query rows per attention block
#define KT 32                         // K rows staged per LDS tile
#define KST 66                        // padded LDS stride (floats): 2-way bank alias = free
#define ATTN_BLOCKS (B * N / TI)      // 512  (attention blocks come FIRST: co-resident at t=0)
#define COPY_BLOCKS 8192
#define COPY_F4     (B * (size_t)N * N * 32 / 4)             // 16,777,216 float4
#define COPY_ITERS  (COPY_F4 / ((size_t)COPY_BLOCKS * 256))  // 8

// ---------------- QKV projection ----------------
// grid: B*N/ROWS blocks, 192 threads (3 waves: Q, K, V)
__global__ __launch_bounds__(192) void qkv_kernel(
    const float* __restrict__ x, const int* __restrict__ mask,
    const float* __restrict__ Wq, const float* __restrict__ bq,
    const float* __restrict__ Wk, const float* __restrict__ bk,
    const float* __restrict__ Wv, const float* __restrict__ bv,
    float* __restrict__ Q, float* __restrict__ K, float* __restrict__ V)
{
    __shared__ float xs[ROWS * D];
    const int tid  = threadIdx.x;
    const int row0 = blockIdx.x * ROWS;

    const float4* x4  = (const float4*)(x + (size_t)row0 * D);
    float4*       xs4 = (float4*)xs;
    for (int i = tid; i < ROWS * D / 4; i += 192) xs4[i] = x4[i];
    __syncthreads();

    const int which = tid >> 6;   // wave-uniform: 0=Q,1=K,2=V
    const int o     = tid & 63;
    const float* W    = (which == 0) ? Wq : (which == 1) ? Wk : Wv;
    const float* bias = (which == 0) ? bq : (which == 1) ? bk : bv;
    float*       Out  = (which == 0) ? Q  : (which == 1) ? K  : V;

    float acc[ROWS];
    const float bo = bias[o];
#pragma unroll
    for (int r = 0; r < ROWS; ++r) acc[r] = bo;

    for (int k = 0; k < D; ++k) {
        const float w = W[k * DH + o];     // coalesced per wave, L2-hot
#pragma unroll
        for (int r = 0; r < ROWS; ++r)
            acc[r] += xs[r * D + k] * w;   // LDS broadcast
    }

#pragma unroll
    for (int r = 0; r < ROWS; ++r) {
        const int row = row0 + r;
        const float m = (float)mask[row];
        Out[(size_t)row * DH + o] = acc[r] * m;
    }
}

// ---------------- fused: tiled attention (blocks 0..511) + e-copy (rest) ----------
// Attention blocks are the LOW indices so all 512 are resident at t=0 (2/CU);
// copy blocks fill remaining slots immediately -> attention hides under the HBM copy.
// Static LDS ~29 KB -> 5 blocks/CU, keeps copy occupancy healthy.
__global__ __launch_bounds__(256) void fused_attn_copy(
    const float* __restrict__ Q, const float* __restrict__ K,
    const float* __restrict__ V, const int* __restrict__ mask,
    const float4* __restrict__ e4, float4* __restrict__ eout4,
    float* __restrict__ out)
{
    const int tid = threadIdx.x;

    __shared__ float qs[TI][DH];    // 2 KB
    __shared__ float sc[TI][N];     // 16 KB  (scores, then p=exp(s-m))
    __shared__ float ks[KT][KST];   // 8.25 KB coalesced K tile, pad->2-way alias (free)
    __shared__ int   msk[N];        // 2 KB

    if (blockIdx.x >= ATTN_BLOCKS) {
        // ---- e passthrough: float4 grid-strided copy at HBM rate ----
        const size_t stride = (size_t)COPY_BLOCKS * 256;
        size_t idx = (size_t)(blockIdx.x - ATTN_BLOCKS) * 256 + tid;
#pragma unroll
        for (int r = 0; r < (int)COPY_ITERS; ++r) {
            eout4[idx] = e4[idx];
            idx += stride;
        }
        return;
    }

    // ---- attention: one block per (b, 8 query rows) ----
    const int b  = blockIdx.x >> 6;          // 64 tiles per batch
    const int i0 = (blockIdx.x & 63) * TI;

    // stage mask (whole batch row-mask) + Q tile
    for (int t = tid; t < N; t += 256) msk[t] = mask[b * N + t];
    if (tid < TI * DH / 4)
        ((float4*)qs)[tid] = ((const float4*)(Q + (size_t)(b * N + i0) * DH))[tid];

    // ---- scores: S = Q K^T / 8, K staged in coalesced LDS tiles ----
    const int jl = tid & 31;     // key within tile
    const int il = tid >> 5;     // query row 0..7
#pragma unroll 1
    for (int jt = 0; jt < N / KT; ++jt) {
        __syncthreads();                     // prior tile's reads done (also orders qs/msk init)
        const float4* kg = (const float4*)(K + (size_t)(b * N + jt * KT) * DH);
#pragma unroll
        for (int u = 0; u < 2; ++u) {        // 512 float4, coalesced
            const int g  = tid + u * 256;
            const int jj = g >> 4;
            const int dd = (g & 15) * 4;
            const float4 kv = kg[g];
            float2* dst = (float2*)&ks[jj][dd];   // 8B-aligned (KST even)
            dst[0] = make_float2(kv.x, kv.y);
            dst[1] = make_float2(kv.z, kv.w);
        }
        __syncthreads();
        float acc = 0.0f;
#pragma unroll
        for (int k = 0; k < DH; ++k)
            acc += qs[il][k] * ks[jl][k];    // broadcast + conflict-free reads
        const int j = jt * KT + jl;
        sc[il][j] = msk[j] ? acc * 0.125f : NEG_INF;
    }
    __syncthreads();

    // ---- softmax: wave w owns rows w and w+4 (wave-private from here on) ----
    const int w = tid >> 6;
    const int o = tid & 63;
    float inv0 = 0.0f, inv1 = 0.0f;
#pragma unroll
    for (int r = 0; r < 2; ++r) {
        const int i = w + r * 4;
        float sv[8];
        float m = -3.402823466e38f;
#pragma unroll
        for (int u = 0; u < 8; ++u) { sv[u] = sc[i][o + u * 64]; m = fmaxf(m, sv[u]); }
#pragma unroll
        for (int off = 32; off; off >>= 1) m = fmaxf(m, __shfl_xor(m, off));
        float sum = 0.0f;
#pragma unroll
        for (int u = 0; u < 8; ++u) { sv[u] = __expf(sv[u] - m); sum += sv[u]; }
#pragma unroll
        for (int off = 32; off; off >>= 1) sum += __shfl_xor(sum, off);
#pragma unroll
        for (int u = 0; u < 8; ++u) sc[i][o + u * 64] = sv[u];
        if (r == 0) inv0 = 1.0f / sum; else inv1 = 1.0f / sum;
    }
    // no barrier needed: wave w wrote and now reads only rows w, w+4

    // ---- PV: lane o = output column (coalesced V reads), 2 rows per thread ----
    const float* vb = V + (size_t)(b * N) * DH + o;
    float a0 = 0.0f, a1 = 0.0f;
#pragma unroll 8
    for (int j = 0; j < N; ++j) {
        const float v = vb[(size_t)j * DH];  // 256B/wave, L2-hot
        a0 += sc[w][j]     * v;              // LDS broadcast
        a1 += sc[w + 4][j] * v;
    }
    const int ra = i0 + w, rb = i0 + w + 4;
    out[(size_t)(b * N + ra) * DH + o] = msk[ra] ? a0 * inv0 : 0.0f;
    out[(size_t)(b * N + rb) * DH + o] = msk[rb] ? a1 * inv1 : 0.0f;
}

extern "C" void kernel_launch(void* const* d_in, const int* in_sizes, int n_in,
                              void* d_out, int out_size, void* d_ws, size_t ws_size,
                              hipStream_t stream)
{
    const float* x    = (const float*)d_in[0];
    const float* e    = (const float*)d_in[1];
    const int*   mask = (const int*)  d_in[2];
    const float* Wq   = (const float*)d_in[3];
    const float* bq   = (const float*)d_in[4];
    const float* Wk   = (const float*)d_in[5];
    const float* bk   = (const float*)d_in[6];
    const float* Wv   = (const float*)d_in[7];
    const float* bv   = (const float*)d_in[8];

    float* out  = (float*)d_out;                    // (B,N,DH) first
    float* eout = out + (size_t)B * N * DH;         // then e passthrough

    float* Q = (float*)d_ws;
    float* K = Q + (size_t)B * N * DH;
    float* V = K + (size_t)B * N * DH;

    qkv_kernel<<<B * N / ROWS, 192, 0, stream>>>(x, mask, Wq, bq, Wk, bk, Wv, bv, Q, K, V);
    fused_attn_copy<<<ATTN_BLOCKS + COPY_BLOCKS, 256, 0, stream>>>(
        Q, K, V, mask, (const float4*)e, (float4*)eout, out);
}